// Round 8
// baseline (496.785 us; speedup 1.0000x reference)
//
#include <hip/hip_runtime.h>

#define NNODES 50000
#define NEDGES 1600000
constexpr int IN_SIZE = 128;
constexpr int HH1 = 64;    // heads*hidden  (8*8)
constexpr int SCAN_B = (NNODES + 1023) / 1024;   // 49
constexpr int RNODES = 6250;                     // 50000 / 8 XCD ranges

typedef __attribute__((ext_vector_type(8))) unsigned short ushort8v;

__device__ inline unsigned short f2bf(float x) {        // RNE float->bf16
    unsigned u = __float_as_uint(x);
    return (unsigned short)((u + 0x7FFFu + ((u >> 16) & 1u)) >> 16);
}
__device__ inline float bf2f(unsigned short u) {
    return __uint_as_float(((unsigned)u) << 16);
}

// ---------------- CSR build (XCD-range-partitioned atomics/writes) ----------------
// Blocks with bid&7==r handle only dst in [r*6250, (r+1)*6250): with round-robin
// block->XCD dispatch each XCD's L2 keeps its 0.8MB adj slice + cursor slice resident.

__global__ __launch_bounds__(256) void hist_kernel(const int* __restrict__ dst, int* __restrict__ counts) {
    int range = blockIdx.x & 7;
    int lo = range * RNODES, hi = lo + RNODES;
    int stride = (gridDim.x >> 3) * 256;
    for (int e = (blockIdx.x >> 3) * 256 + threadIdx.x; e < NEDGES; e += stride) {
        int d = dst[e];
        if (d >= lo && d < hi) atomicAdd(&counts[d], 1);
    }
}

__global__ __launch_bounds__(1024) void scan1_kernel(const int* __restrict__ counts,
                                                     int* __restrict__ row_start,
                                                     int* __restrict__ partials) {
    __shared__ int buf[1024];
    int tid = threadIdx.x;
    int idx = blockIdx.x * 1024 + tid;
    int v = (idx < NNODES) ? counts[idx] : 0;
    buf[tid] = v;
    __syncthreads();
    for (int off = 1; off < 1024; off <<= 1) {
        int t = (tid >= off) ? buf[tid - off] : 0;
        __syncthreads();
        buf[tid] += t;
        __syncthreads();
    }
    if (idx < NNODES) row_start[idx] = buf[tid] - v;
    if (tid == 1023) partials[blockIdx.x] = buf[1023];
}

__global__ __launch_bounds__(64) void scan2_kernel(int* __restrict__ partials) {
    int lane = threadIdx.x;
    int v = (lane < SCAN_B) ? partials[lane] : 0;
    int own = v;
    for (int off = 1; off < 64; off <<= 1) {
        int t = __shfl_up(v, off);
        if (lane >= off) v += t;
    }
    if (lane < SCAN_B) partials[lane] = v - own;
}

__global__ __launch_bounds__(1024) void scan3_kernel(int* __restrict__ row_start,
                                                     const int* __restrict__ partials,
                                                     int* __restrict__ cursor) {
    int idx = blockIdx.x * 1024 + threadIdx.x;
    if (idx < NNODES) {
        int v = row_start[idx] + partials[blockIdx.x];
        row_start[idx] = v;
        cursor[idx] = v;
    }
    if (idx == 0) row_start[NNODES] = NEDGES;
}

__global__ __launch_bounds__(256) void scatter_kernel(const int* __restrict__ src, const int* __restrict__ dst,
                                                      int* __restrict__ cursor, int* __restrict__ adj) {
    int range = blockIdx.x & 7;
    int lo = range * RNODES, hi = lo + RNODES;
    int stride = (gridDim.x >> 3) * 256;
    for (int e = (blockIdx.x >> 3) * 256 + threadIdx.x; e < NEDGES; e += stride) {
        int d = dst[e];
        int s = src[e];
        if (d >= lo && d < hi) {
            int pos = atomicAdd(&cursor[d], 1);
            adj[pos] = s;
        }
    }
}

// ---------------- Layer 1 GEMM + attention coefficients (feat stored bf16) ----------------
// 32 nodes/block (2 iters of 16); each thread: 4 nodes x 1 channel, float4 Xs reads.

__global__ __launch_bounds__(256) void gemm1_kernel(const float* __restrict__ X, const float* __restrict__ W,
                                                    const float* __restrict__ al, const float* __restrict__ ar,
                                                    unsigned short* __restrict__ featb, float* __restrict__ el,
                                                    float* __restrict__ er) {
    __shared__ float Ws[IN_SIZE * HH1];     // 32 KB
    __shared__ float Xs[16][IN_SIZE];       // 8 KB
    __shared__ float Fs[16][HH1 + 4];       // padded: no epilogue bank conflicts
    int tid = threadIdx.x;
    for (int i = tid; i < IN_SIZE * HH1; i += 256) Ws[i] = W[i];
    int c = tid & 63;
    int g = tid >> 6;          // wave id 0..3 -> nodes g*4..g*4+3
    int n0 = g * 4;
    for (int it = 0; it < 2; ++it) {
        int nb = blockIdx.x * 32 + it * 16;
        __syncthreads();
        for (int i = tid; i < 16 * (IN_SIZE / 4); i += 256) {
            int r = i >> 5, k4 = i & 31;
            int nn = nb + r;
            float4 v = (nn < NNODES) ? ((const float4*)(X + (size_t)nn * IN_SIZE))[k4]
                                     : float4{0.f, 0.f, 0.f, 0.f};
            *(float4*)&Xs[r][k4 * 4] = v;
        }
        __syncthreads();
        float acc0 = 0.f, acc1 = 0.f, acc2 = 0.f, acc3 = 0.f;
        for (int k = 0; k < IN_SIZE; k += 4) {
            float w0 = Ws[(k + 0) * HH1 + c];
            float w1 = Ws[(k + 1) * HH1 + c];
            float w2 = Ws[(k + 2) * HH1 + c];
            float w3 = Ws[(k + 3) * HH1 + c];
            float4 x0 = *(const float4*)&Xs[n0 + 0][k];
            float4 x1 = *(const float4*)&Xs[n0 + 1][k];
            float4 x2 = *(const float4*)&Xs[n0 + 2][k];
            float4 x3 = *(const float4*)&Xs[n0 + 3][k];
            acc0 += x0.x * w0 + x0.y * w1 + x0.z * w2 + x0.w * w3;
            acc1 += x1.x * w0 + x1.y * w1 + x1.z * w2 + x1.w * w3;
            acc2 += x2.x * w0 + x2.y * w1 + x2.z * w2 + x2.w * w3;
            acc3 += x3.x * w0 + x3.y * w1 + x3.z * w2 + x3.w * w3;
        }
        int n = nb + n0;
        if (n + 0 < NNODES) featb[(size_t)(n + 0) * HH1 + c] = f2bf(acc0);
        if (n + 1 < NNODES) featb[(size_t)(n + 1) * HH1 + c] = f2bf(acc1);
        if (n + 2 < NNODES) featb[(size_t)(n + 2) * HH1 + c] = f2bf(acc2);
        if (n + 3 < NNODES) featb[(size_t)(n + 3) * HH1 + c] = f2bf(acc3);
        Fs[n0 + 0][c] = acc0;
        Fs[n0 + 1][c] = acc1;
        Fs[n0 + 2][c] = acc2;
        Fs[n0 + 3][c] = acc3;
        __syncthreads();
        {
            int t2 = tid & 127;
            int j = t2 >> 3, h = t2 & 7;
            int nn = nb + j;
            const float* a = (tid < 128) ? al : ar;
            float s = 0.f;
#pragma unroll
            for (int d = 0; d < 8; ++d) s += Fs[j][h * 8 + d] * a[h * 8 + d];
            if (nn < NNODES) { if (tid < 128) el[nn * 8 + h] = s; else er[nn * 8 + h] = s; }
        }
    }
}

// ---------------- Layer 1 aggregation: one wave per dst node, 8-wide, bf16 gathers ----------------
// Scores are O(+-4) so exp() without max-subtraction is exact in fp32 (softmax shift-invariant).

__global__ __launch_bounds__(256) void agg1_kernel(const int* __restrict__ row_start, const int* __restrict__ adj,
                                                   const unsigned short* __restrict__ featb,
                                                   const float* __restrict__ el, const float* __restrict__ er,
                                                   const float* __restrict__ b,
                                                   float* __restrict__ hout, unsigned short* __restrict__ houtb) {
    int n = (blockIdx.x * blockDim.x + threadIdx.x) >> 6;
    if (n >= NNODES) return;
    int lane = threadIdx.x & 63;
    int h = lane >> 3;
    int s0 = row_start[n], s1 = row_start[n + 1];
    float erh = er[n * 8 + h];
    float denom = 0.f, acc = 0.f;
    int i = s0;
    for (; i + 7 < s1; i += 8) {
        int s[8];
#pragma unroll
        for (int j = 0; j < 8; ++j) s[j] = adj[i + j];
        float e[8], f[8];
#pragma unroll
        for (int j = 0; j < 8; ++j) e[j] = el[s[j] * 8 + h] + erh;
#pragma unroll
        for (int j = 0; j < 8; ++j) f[j] = bf2f(featb[(size_t)s[j] * HH1 + lane]);
#pragma unroll
        for (int j = 0; j < 8; ++j) {
            float ee = (e[j] >= 0.f) ? e[j] : 0.2f * e[j];
            float w = __expf(ee);
            denom += w;
            acc += w * f[j];
        }
    }
    for (; i < s1; ++i) {
        int s = adj[i];
        float e = el[s * 8 + h] + erh; e = (e >= 0.f) ? e : 0.2f * e;
        float f = bf2f(featb[(size_t)s * HH1 + lane]);
        float w = __expf(e);
        denom += w;
        acc += w * f;
    }
    float val = (s1 > s0) ? acc / denom : 0.f;
    val += b[lane];
    val = (val > 0.f) ? val : expm1f(val);   // ELU
    hout[(size_t)n * HH1 + lane] = val;      // fp32 copy for el2er2
    houtb[(size_t)n * HH1 + lane] = f2bf(val);  // bf16 copy for agg2h gather
}

// ---------------- projected attention vectors for layer 2 ----------------

__global__ __launch_bounds__(512) void prep_wel_kernel(const float* __restrict__ W2, const float* __restrict__ al2,
                                                       const float* __restrict__ ar2,
                                                       float* __restrict__ wel, float* __restrict__ wer) {
    int t = threadIdx.x;           // 0..511 = h*64+d
    int h = t >> 6, d = t & 63;
    float se = 0.f, sr = 0.f;
#pragma unroll
    for (int o = 0; o < 32; ++o) {
        float w = W2[d * 256 + h * 32 + o];
        se += w * al2[h * 32 + o];
        sr += w * ar2[h * 32 + o];
    }
    wel[t] = se;
    wer[t] = sr;
}

__global__ __launch_bounds__(256) void el2er2_kernel(const float* __restrict__ h1, const float* __restrict__ wel,
                                                     const float* __restrict__ wer,
                                                     float* __restrict__ el2, float* __restrict__ er2) {
    __shared__ float wsT[512];
    __shared__ float wrT[512];
    int t = threadIdx.x;
    for (int i = t; i < 512; i += 256) {
        int d = i >> 3, h = i & 7;
        wsT[i] = wel[h * 64 + d];
        wrT[i] = wer[h * 64 + d];
    }
    __syncthreads();
    int n = blockIdx.x * 32 + (t >> 3);
    int h = t & 7;
    if (n >= NNODES) return;
    const float4* hr = (const float4*)(h1 + (size_t)n * 64);
    float se = 0.f, sr = 0.f;
#pragma unroll
    for (int d4 = 0; d4 < 16; ++d4) {
        float4 v = hr[d4];
        int base = d4 * 32 + h;
        se += v.x * wsT[base] + v.y * wsT[base + 8] + v.z * wsT[base + 16] + v.w * wsT[base + 24];
        sr += v.x * wrT[base] + v.y * wrT[base + 8] + v.z * wrT[base + 16] + v.w * wrT[base + 24];
    }
    el2[n * 8 + h] = se;
    er2[n * 8 + h] = sr;
}

// ---------------- Layer 2 aggregation in h1-space, bf16 gathers ----------------

__global__ __launch_bounds__(256) void agg2h_kernel(const int* __restrict__ row_start, const int* __restrict__ adj,
                                                    const unsigned short* __restrict__ h1b,
                                                    const float* __restrict__ el2, const float* __restrict__ er2,
                                                    float* __restrict__ aggbuf) {
    int n = (blockIdx.x * blockDim.x + threadIdx.x) >> 6;
    if (n >= NNODES) return;
    int lane = threadIdx.x & 63;
    int h = lane >> 3;
    int db = lane & 7;
    int s0 = row_start[n], s1 = row_start[n + 1];
    float erh = er2[n * 8 + h];
    float denom = 0.f;
    float a0 = 0.f, a1 = 0.f, a2 = 0.f, a3 = 0.f, a4 = 0.f, a5 = 0.f, a6 = 0.f, a7 = 0.f;
    const unsigned short* h1l = h1b + db * 8;
    int i = s0;
    for (; i + 3 < s1; i += 4) {
        int sA = adj[i], sB = adj[i + 1], sC = adj[i + 2], sD = adj[i + 3];
        float eA = el2[sA * 8 + h] + erh;
        float eB = el2[sB * 8 + h] + erh;
        float eC = el2[sC * 8 + h] + erh;
        float eD = el2[sD * 8 + h] + erh;
        ushort8v rA = *(const ushort8v*)(h1l + (size_t)sA * 64);
        ushort8v rB = *(const ushort8v*)(h1l + (size_t)sB * 64);
        ushort8v rC = *(const ushort8v*)(h1l + (size_t)sC * 64);
        ushort8v rD = *(const ushort8v*)(h1l + (size_t)sD * 64);
        eA = (eA >= 0.f) ? eA : 0.2f * eA;
        eB = (eB >= 0.f) ? eB : 0.2f * eB;
        eC = (eC >= 0.f) ? eC : 0.2f * eC;
        eD = (eD >= 0.f) ? eD : 0.2f * eD;
        float wA = __expf(eA), wB = __expf(eB), wC = __expf(eC), wD = __expf(eD);
        denom += (wA + wB) + (wC + wD);
        a0 += (wA * bf2f(rA[0]) + wB * bf2f(rB[0])) + (wC * bf2f(rC[0]) + wD * bf2f(rD[0]));
        a1 += (wA * bf2f(rA[1]) + wB * bf2f(rB[1])) + (wC * bf2f(rC[1]) + wD * bf2f(rD[1]));
        a2 += (wA * bf2f(rA[2]) + wB * bf2f(rB[2])) + (wC * bf2f(rC[2]) + wD * bf2f(rD[2]));
        a3 += (wA * bf2f(rA[3]) + wB * bf2f(rB[3])) + (wC * bf2f(rC[3]) + wD * bf2f(rD[3]));
        a4 += (wA * bf2f(rA[4]) + wB * bf2f(rB[4])) + (wC * bf2f(rC[4]) + wD * bf2f(rD[4]));
        a5 += (wA * bf2f(rA[5]) + wB * bf2f(rB[5])) + (wC * bf2f(rC[5]) + wD * bf2f(rD[5]));
        a6 += (wA * bf2f(rA[6]) + wB * bf2f(rB[6])) + (wC * bf2f(rC[6]) + wD * bf2f(rD[6]));
        a7 += (wA * bf2f(rA[7]) + wB * bf2f(rB[7])) + (wC * bf2f(rC[7]) + wD * bf2f(rD[7]));
    }
    for (; i < s1; ++i) {
        int s = adj[i];
        float e = el2[s * 8 + h] + erh; e = (e >= 0.f) ? e : 0.2f * e;
        ushort8v r = *(const ushort8v*)(h1l + (size_t)s * 64);
        float w = __expf(e);
        denom += w;
        a0 += w * bf2f(r[0]); a1 += w * bf2f(r[1]); a2 += w * bf2f(r[2]); a3 += w * bf2f(r[3]);
        a4 += w * bf2f(r[4]); a5 += w * bf2f(r[5]); a6 += w * bf2f(r[6]); a7 += w * bf2f(r[7]);
    }
    float inv = (s1 > s0) ? 1.f / denom : 0.f;
    float* o = aggbuf + (size_t)n * 512 + lane * 8;
    float4 o0 = { a0 * inv, a1 * inv, a2 * inv, a3 * inv };
    float4 o1 = { a4 * inv, a5 * inv, a6 * inv, a7 * inv };
    ((float4*)o)[0] = o0;
    ((float4*)o)[1] = o1;
}

// ---------------- final GEMM: out[n,jo] = (1/8) sum_k aggbuf[n,k] * W2perm[k,jo] + bconst[jo] ----------------

__global__ __launch_bounds__(256) void gemm3_kernel(const float* __restrict__ aggbuf, const float* __restrict__ W2,
                                                    const float* __restrict__ b2, float* __restrict__ out) {
    __shared__ float Bs[512 * 32];    // 64 KB, pre-scaled by 1/8
    int t = threadIdx.x;
    for (int i = t; i < 512 * 32; i += 256) {
        int k = i >> 5, jo = i & 31;
        int d = k & 63, h = k >> 6;
        Bs[i] = W2[d * 256 + h * 32 + jo] * 0.125f;
    }
    int cg = t & 7;
    float bx = 0.f, by = 0.f, bz = 0.f, bw = 0.f;
#pragma unroll
    for (int h = 0; h < 8; ++h) {
        const float* bp = b2 + h * 32 + cg * 4;
        bx += bp[0]; by += bp[1]; bz += bp[2]; bw += bp[3];
    }
    bx *= 0.125f; by *= 0.125f; bz *= 0.125f; bw *= 0.125f;
    __syncthreads();
    int n = blockIdx.x * 32 + (t >> 3);
    if (n >= NNODES) return;
    const float4* ar = (const float4*)(aggbuf + (size_t)n * 512);
    float accx = bx, accy = by, accz = bz, accw = bw;
    for (int k4 = 0; k4 < 128; ++k4) {
        float4 a = ar[k4];
        const float* base = Bs + (k4 * 4) * 32 + cg * 4;
        float4 b0 = *(const float4*)(base);
        float4 b1 = *(const float4*)(base + 32);
        float4 b2v = *(const float4*)(base + 64);
        float4 b3 = *(const float4*)(base + 96);
        accx += a.x * b0.x + a.y * b1.x + a.z * b2v.x + a.w * b3.x;
        accy += a.x * b0.y + a.y * b1.y + a.z * b2v.y + a.w * b3.y;
        accz += a.x * b0.z + a.y * b1.z + a.z * b2v.z + a.w * b3.z;
        accw += a.x * b0.w + a.y * b1.w + a.z * b2v.w + a.w * b3.w;
    }
    float4 o = { accx, accy, accz, accw };
    *(float4*)(out + (size_t)n * 32 + cg * 4) = o;
}

// ---------------- launch ----------------

extern "C" void kernel_launch(void* const* d_in, const int* in_sizes, int n_in,
                              void* d_out, int out_size, void* d_ws, size_t ws_size,
                              hipStream_t stream) {
    const float* node_feat = (const float*)d_in[0];
    const float* W1  = (const float*)d_in[1];
    const float* al1 = (const float*)d_in[2];
    const float* ar1 = (const float*)d_in[3];
    const float* b1  = (const float*)d_in[4];
    const float* W2  = (const float*)d_in[5];
    const float* al2 = (const float*)d_in[6];
    const float* ar2 = (const float*)d_in[7];
    const float* b2  = (const float*)d_in[8];
    const int* src = (const int*)d_in[9];
    const int* dst = (const int*)d_in[10];
    float* out = (float*)d_out;

    float* p = (float*)d_ws;
    float* aggbuf = p; p += (size_t)NNODES * 512;          // 102.4 MB
    // featb/el1/er1 overlap aggbuf (dead before aggbuf is written)
    unsigned short* featb = (unsigned short*)aggbuf;                 // 6.4 MB
    float* el1 = (float*)(featb + (size_t)NNODES * HH1);
    float* er1 = el1 + NNODES * 8;
    float* h1  = p; p += (size_t)NNODES * HH1;             // 12.8 MB fp32
    unsigned short* h1b = (unsigned short*)p; p += (size_t)NNODES * HH1 / 2;  // 6.4 MB bf16
    float* el2 = p; p += NNODES * 8;
    float* er2 = p; p += NNODES * 8;
    float* wel = p; p += 512;
    float* wer = p; p += 512;
    int* counts    = (int*)p;
    int* row_start = counts + NNODES;
    int* partials  = row_start + NNODES + 1;
    int* cursor    = partials + 64;
    int* adj       = cursor + NNODES;

    hipMemsetAsync(counts, 0, NNODES * sizeof(int), stream);
    hist_kernel<<<512, 256, 0, stream>>>(dst, counts);
    scan1_kernel<<<SCAN_B, 1024, 0, stream>>>(counts, row_start, partials);
    scan2_kernel<<<1, 64, 0, stream>>>(partials);
    scan3_kernel<<<SCAN_B, 1024, 0, stream>>>(row_start, partials, cursor);
    scatter_kernel<<<512, 256, 0, stream>>>(src, dst, cursor, adj);
    gemm1_kernel<<<(NNODES + 31) / 32, 256, 0, stream>>>(node_feat, W1, al1, ar1, featb, el1, er1);
    prep_wel_kernel<<<1, 512, 0, stream>>>(W2, al2, ar2, wel, wer);
    agg1_kernel<<<(NNODES + 3) / 4, 256, 0, stream>>>(row_start, adj, featb, el1, er1, b1, h1, h1b);
    el2er2_kernel<<<(NNODES + 31) / 32, 256, 0, stream>>>(h1, wel, wer, el2, er2);
    agg2h_kernel<<<(NNODES + 3) / 4, 256, 0, stream>>>(row_start, adj, h1b, el2, er2, aggbuf);
    gemm3_kernel<<<(NNODES + 31) / 32, 256, 0, stream>>>(aggbuf, W2, b2, out);
}

// Round 10
// 426.140 us; speedup vs baseline: 1.1658x; 1.1658x over previous
//
#include <hip/hip_runtime.h>

#define NNODES 50000
#define NEDGES 1600000
constexpr int IN_SIZE = 128;
constexpr int HH1 = 64;    // heads*hidden  (8*8)
constexpr int SCAN_B = (NNODES + 1023) / 1024;   // 49
constexpr int RNODES = 6250;                     // 50000 / 8 XCD ranges
#define LOG2E 1.44269504088896f

typedef __attribute__((ext_vector_type(2))) float float2v;

__device__ inline unsigned short f2bf(float x) {        // RNE float->bf16
    unsigned u = __float_as_uint(x);
    return (unsigned short)((u + 0x7FFFu + ((u >> 16) & 1u)) >> 16);
}
__device__ inline float bf2f(unsigned short u) {
    return __uint_as_float(((unsigned)u) << 16);
}
__device__ inline float2v bfpair(unsigned u) {          // 2 bf16 in one u32 -> float2
    float2v r;
    r.x = __uint_as_float(u << 16);
    r.y = __uint_as_float(u & 0xFFFF0000u);
    return r;
}
__device__ inline float fexp2(float x) {
#if __has_builtin(__builtin_amdgcn_exp2f)
    return __builtin_amdgcn_exp2f(x);
#else
    return exp2f(x);
#endif
}

// ---------------- CSR build (XCD-range-partitioned atomics/writes) ----------------

__global__ __launch_bounds__(256) void hist_kernel(const int* __restrict__ dst, int* __restrict__ counts) {
    int range = blockIdx.x & 7;
    int lo = range * RNODES, hi = lo + RNODES;
    int stride = (gridDim.x >> 3) * 256;
    for (int e = (blockIdx.x >> 3) * 256 + threadIdx.x; e < NEDGES; e += stride) {
        int d = dst[e];
        if (d >= lo && d < hi) atomicAdd(&counts[d], 1);
    }
}

__global__ __launch_bounds__(1024) void scan1_kernel(const int* __restrict__ counts,
                                                     int* __restrict__ row_start,
                                                     int* __restrict__ partials) {
    __shared__ int buf[1024];
    int tid = threadIdx.x;
    int idx = blockIdx.x * 1024 + tid;
    int v = (idx < NNODES) ? counts[idx] : 0;
    buf[tid] = v;
    __syncthreads();
    for (int off = 1; off < 1024; off <<= 1) {
        int t = (tid >= off) ? buf[tid - off] : 0;
        __syncthreads();
        buf[tid] += t;
        __syncthreads();
    }
    if (idx < NNODES) row_start[idx] = buf[tid] - v;
    if (tid == 1023) partials[blockIdx.x] = buf[1023];
}

__global__ __launch_bounds__(64) void scan2_kernel(int* __restrict__ partials) {
    int lane = threadIdx.x;
    int v = (lane < SCAN_B) ? partials[lane] : 0;
    int own = v;
    for (int off = 1; off < 64; off <<= 1) {
        int t = __shfl_up(v, off);
        if (lane >= off) v += t;
    }
    if (lane < SCAN_B) partials[lane] = v - own;
}

__global__ __launch_bounds__(1024) void scan3_kernel(int* __restrict__ row_start,
                                                     const int* __restrict__ partials,
                                                     int* __restrict__ cursor) {
    int idx = blockIdx.x * 1024 + threadIdx.x;
    if (idx < NNODES) {
        int v = row_start[idx] + partials[blockIdx.x];
        row_start[idx] = v;
        cursor[idx] = v;
    }
    if (idx == 0) row_start[NNODES] = NEDGES;
}

__global__ __launch_bounds__(256) void scatter_kernel(const int* __restrict__ src, const int* __restrict__ dst,
                                                      int* __restrict__ cursor, int* __restrict__ adj) {
    int range = blockIdx.x & 7;
    int lo = range * RNODES, hi = lo + RNODES;
    int stride = (gridDim.x >> 3) * 256;
    for (int e = (blockIdx.x >> 3) * 256 + threadIdx.x; e < NEDGES; e += stride) {
        int d = dst[e];
        int s = src[e];
        if (d >= lo && d < hi) {
            int pos = atomicAdd(&cursor[d], 1);
            adj[pos] = s;
        }
    }
}

// ---------------- Layer 1 GEMM + attention coefficients (R6 structure, feat bf16) ----------------
// el/er pre-scaled by log2(e) so agg kernels can use v_exp_f32 (exp2) directly.

__global__ __launch_bounds__(256) void gemm1_kernel(const float* __restrict__ X, const float* __restrict__ W,
                                                    const float* __restrict__ al, const float* __restrict__ ar,
                                                    unsigned short* __restrict__ featb, float* __restrict__ el,
                                                    float* __restrict__ er) {
    __shared__ float Ws[IN_SIZE * HH1];   // 32 KB
    __shared__ float Xs[4][IN_SIZE];
    __shared__ float Fs[4][HH1];
    int tid = threadIdx.x;
    for (int i = tid; i < IN_SIZE * HH1; i += 256) Ws[i] = W[i];
    int ln = tid >> 6;
    int c  = tid & 63;
    for (int it = 0; it < 2; ++it) {
        int nb = blockIdx.x * 8 + it * 4;
        __syncthreads();
        for (int i = tid; i < 4 * IN_SIZE; i += 256) {
            int r = i >> 7, k = i & 127;
            int nn = nb + r;
            Xs[r][k] = (nn < NNODES) ? X[(size_t)nn * IN_SIZE + k] : 0.f;
        }
        __syncthreads();
        float acc = 0.f;
#pragma unroll
        for (int k = 0; k < IN_SIZE; ++k) acc += Xs[ln][k] * Ws[k * HH1 + c];
        int n = nb + ln;
        if (n < NNODES) featb[(size_t)n * HH1 + c] = f2bf(acc);
        Fs[ln][c] = acc;
        __syncthreads();
        if (c < 16 && n < NNODES) {
            int h = c & 7;
            const float* a = (c < 8) ? al : ar;
            float s = 0.f;
#pragma unroll
            for (int d = 0; d < 8; ++d) s += Fs[ln][h * 8 + d] * a[h * 8 + d];
            s *= LOG2E;
            if (c < 8) el[n * 8 + h] = s; else er[n * 8 + h] = s;
        }
    }
}

// ---------------- Layer 1 aggregation: one wave per dst node, 8-wide, bf16 gathers ----------------
// Scores O(+-6): exp2 without max-subtraction exact in fp32 (softmax shift-invariant).

__global__ __launch_bounds__(256) void agg1_kernel(const int* __restrict__ row_start, const int* __restrict__ adj,
                                                   const unsigned short* __restrict__ featb,
                                                   const float* __restrict__ el, const float* __restrict__ er,
                                                   const float* __restrict__ b,
                                                   float* __restrict__ hout, unsigned short* __restrict__ houtb) {
    int n = (blockIdx.x * blockDim.x + threadIdx.x) >> 6;
    if (n >= NNODES) return;
    int lane = threadIdx.x & 63;
    int h = lane >> 3;
    int s0 = row_start[n], s1 = row_start[n + 1];
    float erh = er[n * 8 + h];
    float denom = 0.f, acc = 0.f;
    int i = s0;
    for (; i + 7 < s1; i += 8) {
        int s[8];
#pragma unroll
        for (int j = 0; j < 8; ++j) s[j] = adj[i + j];
        float e[8], f[8];
#pragma unroll
        for (int j = 0; j < 8; ++j) e[j] = el[s[j] * 8 + h] + erh;
#pragma unroll
        for (int j = 0; j < 8; ++j) f[j] = bf2f(featb[(size_t)s[j] * HH1 + lane]);
#pragma unroll
        for (int j = 0; j < 8; ++j) {
            float ee = (e[j] >= 0.f) ? e[j] : 0.2f * e[j];
            float w = fexp2(ee);
            denom += w;
            acc += w * f[j];
        }
    }
    for (; i < s1; ++i) {
        int s = adj[i];
        float e = el[s * 8 + h] + erh; e = (e >= 0.f) ? e : 0.2f * e;
        float f = bf2f(featb[(size_t)s * HH1 + lane]);
        float w = fexp2(e);
        denom += w;
        acc += w * f;
    }
    float val = (s1 > s0) ? acc / denom : 0.f;
    val += b[lane];
    val = (val > 0.f) ? val : expm1f(val);   // ELU
    hout[(size_t)n * HH1 + lane] = val;      // fp32 copy for el2er2
    houtb[(size_t)n * HH1 + lane] = f2bf(val);  // bf16 copy for agg2h gather
}

// ---------------- projected attention vectors for layer 2 (pre-scaled by log2e) ----------------

__global__ __launch_bounds__(512) void prep_wel_kernel(const float* __restrict__ W2, const float* __restrict__ al2,
                                                       const float* __restrict__ ar2,
                                                       float* __restrict__ wel, float* __restrict__ wer) {
    int t = threadIdx.x;           // 0..511 = h*64+d
    int h = t >> 6, d = t & 63;
    float se = 0.f, sr = 0.f;
#pragma unroll
    for (int o = 0; o < 32; ++o) {
        float w = W2[d * 256 + h * 32 + o];
        se += w * al2[h * 32 + o];
        sr += w * ar2[h * 32 + o];
    }
    wel[t] = se * LOG2E;
    wer[t] = sr * LOG2E;
}

__global__ __launch_bounds__(256) void el2er2_kernel(const float* __restrict__ h1, const float* __restrict__ wel,
                                                     const float* __restrict__ wer,
                                                     float* __restrict__ el2, float* __restrict__ er2) {
    __shared__ float wsT[512];
    __shared__ float wrT[512];
    int t = threadIdx.x;
    for (int i = t; i < 512; i += 256) {
        int d = i >> 3, h = i & 7;
        wsT[i] = wel[h * 64 + d];
        wrT[i] = wer[h * 64 + d];
    }
    __syncthreads();
    int n = blockIdx.x * 32 + (t >> 3);
    int h = t & 7;
    if (n >= NNODES) return;
    const float4* hr = (const float4*)(h1 + (size_t)n * 64);
    float se = 0.f, sr = 0.f;
#pragma unroll
    for (int d4 = 0; d4 < 16; ++d4) {
        float4 v = hr[d4];
        int base = d4 * 32 + h;
        se += v.x * wsT[base] + v.y * wsT[base + 8] + v.z * wsT[base + 16] + v.w * wsT[base + 24];
        sr += v.x * wrT[base] + v.y * wrT[base + 8] + v.z * wrT[base + 16] + v.w * wrT[base + 24];
    }
    el2[n * 8 + h] = se;
    er2[n * 8 + h] = sr;
}

// ---------------- Layer 2 aggregation in h1-space: bf16 gathers, float2 packed FMA ----------------
// lane = h*8+db owns dims d = db*8..db*8+7 of head h; writes bf16 aggbuf row (512 bf16 = 1KB).

__global__ __launch_bounds__(256) void agg2h_kernel(const int* __restrict__ row_start, const int* __restrict__ adj,
                                                    const unsigned short* __restrict__ h1b,
                                                    const float* __restrict__ el2, const float* __restrict__ er2,
                                                    unsigned short* __restrict__ aggbufb) {
    int n = (blockIdx.x * blockDim.x + threadIdx.x) >> 6;
    if (n >= NNODES) return;
    int lane = threadIdx.x & 63;
    int h = lane >> 3;
    int db = lane & 7;
    int s0 = row_start[n], s1 = row_start[n + 1];
    float erh = er2[n * 8 + h];
    float denom = 0.f;
    float2v p0 = {0.f, 0.f}, p1 = {0.f, 0.f}, p2 = {0.f, 0.f}, p3 = {0.f, 0.f};
    const unsigned short* h1l = h1b + db * 8;
    int i = s0;
    for (; i + 3 < s1; i += 4) {
        int sA = adj[i], sB = adj[i + 1], sC = adj[i + 2], sD = adj[i + 3];
        float eA = el2[sA * 8 + h] + erh;
        float eB = el2[sB * 8 + h] + erh;
        float eC = el2[sC * 8 + h] + erh;
        float eD = el2[sD * 8 + h] + erh;
        uint4 rA = *(const uint4*)(h1l + (size_t)sA * 64);
        uint4 rB = *(const uint4*)(h1l + (size_t)sB * 64);
        uint4 rC = *(const uint4*)(h1l + (size_t)sC * 64);
        uint4 rD = *(const uint4*)(h1l + (size_t)sD * 64);
        eA = (eA >= 0.f) ? eA : 0.2f * eA;
        eB = (eB >= 0.f) ? eB : 0.2f * eB;
        eC = (eC >= 0.f) ? eC : 0.2f * eC;
        eD = (eD >= 0.f) ? eD : 0.2f * eD;
        float wA = fexp2(eA), wB = fexp2(eB), wC = fexp2(eC), wD = fexp2(eD);
        denom += (wA + wB) + (wC + wD);
        p0 += bfpair(rA.x) * wA; p1 += bfpair(rA.y) * wA; p2 += bfpair(rA.z) * wA; p3 += bfpair(rA.w) * wA;
        p0 += bfpair(rB.x) * wB; p1 += bfpair(rB.y) * wB; p2 += bfpair(rB.z) * wB; p3 += bfpair(rB.w) * wB;
        p0 += bfpair(rC.x) * wC; p1 += bfpair(rC.y) * wC; p2 += bfpair(rC.z) * wC; p3 += bfpair(rC.w) * wC;
        p0 += bfpair(rD.x) * wD; p1 += bfpair(rD.y) * wD; p2 += bfpair(rD.z) * wD; p3 += bfpair(rD.w) * wD;
    }
    for (; i < s1; ++i) {
        int s = adj[i];
        float e = el2[s * 8 + h] + erh; e = (e >= 0.f) ? e : 0.2f * e;
        uint4 r = *(const uint4*)(h1l + (size_t)s * 64);
        float w = fexp2(e);
        denom += w;
        p0 += bfpair(r.x) * w; p1 += bfpair(r.y) * w; p2 += bfpair(r.z) * w; p3 += bfpair(r.w) * w;
    }
    float inv = (s1 > s0) ? 1.f / denom : 0.f;
    uint4 o;
    o.x = (unsigned)f2bf(p0.x * inv) | ((unsigned)f2bf(p0.y * inv) << 16);
    o.y = (unsigned)f2bf(p1.x * inv) | ((unsigned)f2bf(p1.y * inv) << 16);
    o.z = (unsigned)f2bf(p2.x * inv) | ((unsigned)f2bf(p2.y * inv) << 16);
    o.w = (unsigned)f2bf(p3.x * inv) | ((unsigned)f2bf(p3.y * inv) << 16);
    *(uint4*)(aggbufb + (size_t)n * 512 + lane * 8) = o;
}

// ---------------- final GEMM: out[n,jo] = (1/8) sum_k agg[n,k] * W2perm[k,jo] + bconst[jo] ----------------
// aggbuf now bf16: read 8 dims (uint4) per iter.

__global__ __launch_bounds__(256) void gemm3_kernel(const unsigned short* __restrict__ aggbufb,
                                                    const float* __restrict__ W2,
                                                    const float* __restrict__ b2, float* __restrict__ out) {
    __shared__ float Bs[512 * 32];    // 64 KB, pre-scaled by 1/8
    int t = threadIdx.x;
    for (int i = t; i < 512 * 32; i += 256) {
        int k = i >> 5, jo = i & 31;
        int d = k & 63, h = k >> 6;
        Bs[i] = W2[d * 256 + h * 32 + jo] * 0.125f;
    }
    int cg = t & 7;
    float bx = 0.f, by = 0.f, bz = 0.f, bw = 0.f;
#pragma unroll
    for (int h = 0; h < 8; ++h) {
        const float* bp = b2 + h * 32 + cg * 4;
        bx += bp[0]; by += bp[1]; bz += bp[2]; bw += bp[3];
    }
    bx *= 0.125f; by *= 0.125f; bz *= 0.125f; bw *= 0.125f;
    __syncthreads();
    int n = blockIdx.x * 32 + (t >> 3);
    if (n >= NNODES) return;
    const uint4* ar = (const uint4*)(aggbufb + (size_t)n * 512);
    float accx = bx, accy = by, accz = bz, accw = bw;
    for (int k8 = 0; k8 < 64; ++k8) {
        uint4 a = ar[k8];
        float2v d01 = bfpair(a.x), d23 = bfpair(a.y), d45 = bfpair(a.z), d67 = bfpair(a.w);
        const float* base = Bs + (k8 * 8) * 32 + cg * 4;
        float4 b0 = *(const float4*)(base);
        float4 b1 = *(const float4*)(base + 32);
        float4 b2v = *(const float4*)(base + 64);
        float4 b3 = *(const float4*)(base + 96);
        float4 b4 = *(const float4*)(base + 128);
        float4 b5 = *(const float4*)(base + 160);
        float4 b6 = *(const float4*)(base + 192);
        float4 b7 = *(const float4*)(base + 224);
        accx += d01.x * b0.x + d01.y * b1.x + d23.x * b2v.x + d23.y * b3.x
              + d45.x * b4.x + d45.y * b5.x + d67.x * b6.x + d67.y * b7.x;
        accy += d01.x * b0.y + d01.y * b1.y + d23.x * b2v.y + d23.y * b3.y
              + d45.x * b4.y + d45.y * b5.y + d67.x * b6.y + d67.y * b7.y;
        accz += d01.x * b0.z + d01.y * b1.z + d23.x * b2v.z + d23.y * b3.z
              + d45.x * b4.z + d45.y * b5.z + d67.x * b6.z + d67.y * b7.z;
        accw += d01.x * b0.w + d01.y * b1.w + d23.x * b2v.w + d23.y * b3.w
              + d45.x * b4.w + d45.y * b5.w + d67.x * b6.w + d67.y * b7.w;
    }
    float4 o = { accx, accy, accz, accw };
    *(float4*)(out + (size_t)n * 32 + cg * 4) = o;
}

// ---------------- launch ----------------

extern "C" void kernel_launch(void* const* d_in, const int* in_sizes, int n_in,
                              void* d_out, int out_size, void* d_ws, size_t ws_size,
                              hipStream_t stream) {
    const float* node_feat = (const float*)d_in[0];
    const float* W1  = (const float*)d_in[1];
    const float* al1 = (const float*)d_in[2];
    const float* ar1 = (const float*)d_in[3];
    const float* b1  = (const float*)d_in[4];
    const float* W2  = (const float*)d_in[5];
    const float* al2 = (const float*)d_in[6];
    const float* ar2 = (const float*)d_in[7];
    const float* b2  = (const float*)d_in[8];
    const int* src = (const int*)d_in[9];
    const int* dst = (const int*)d_in[10];
    float* out = (float*)d_out;

    float* p = (float*)d_ws;
    unsigned short* aggbufb = (unsigned short*)p; p += (size_t)NNODES * 256;   // 51.2 MB (bf16)
    // featb/el1/er1 overlap aggbufb (dead before aggbufb is written)
    unsigned short* featb = aggbufb;                                           // 6.4 MB
    float* el1 = (float*)(featb + (size_t)NNODES * HH1);
    float* er1 = el1 + NNODES * 8;
    float* h1  = p; p += (size_t)NNODES * HH1;             // 12.8 MB fp32
    unsigned short* h1b = (unsigned short*)p; p += (size_t)NNODES * HH1 / 2;  // 6.4 MB bf16
    float* el2 = p; p += NNODES * 8;
    float* er2 = p; p += NNODES * 8;
    float* wel = p; p += 512;
    float* wer = p; p += 512;
    int* counts    = (int*)p;
    int* row_start = counts + NNODES;
    int* partials  = row_start + NNODES + 1;
    int* cursor    = partials + 64;
    int* adj       = cursor + NNODES;

    hipMemsetAsync(counts, 0, NNODES * sizeof(int), stream);
    hist_kernel<<<512, 256, 0, stream>>>(dst, counts);
    scan1_kernel<<<SCAN_B, 1024, 0, stream>>>(counts, row_start, partials);
    scan2_kernel<<<1, 64, 0, stream>>>(partials);
    scan3_kernel<<<SCAN_B, 1024, 0, stream>>>(row_start, partials, cursor);
    scatter_kernel<<<512, 256, 0, stream>>>(src, dst, cursor, adj);
    gemm1_kernel<<<(NNODES + 7) / 8, 256, 0, stream>>>(node_feat, W1, al1, ar1, featb, el1, er1);
    prep_wel_kernel<<<1, 512, 0, stream>>>(W2, al2, ar2, wel, wer);
    agg1_kernel<<<(NNODES + 3) / 4, 256, 0, stream>>>(row_start, adj, featb, el1, er1, b1, h1, h1b);
    el2er2_kernel<<<(NNODES + 31) / 32, 256, 0, stream>>>(h1, wel, wer, el2, er2);
    agg2h_kernel<<<(NNODES + 3) / 4, 256, 0, stream>>>(row_start, adj, h1b, el2, er2, aggbufb);
    gemm3_kernel<<<(NNODES + 31) / 32, 256, 0, stream>>>(aggbufb, W2, b2, out);
}